// Round 13
// baseline (147.631 us; speedup 1.0000x reference)
//
#include <hip/hip_runtime.h>

#define T_N 1024
#define B_N 512
#define HID 20
#define TB3 (T_N * B_N * 3)   // 1572864
#define MEPAD 1152            // me + 128 zero-pad (kl[d<=0] = 0)
#define NBLK 256              // B_N/2 blocks; 2 systems per block

typedef float f4v __attribute__((ext_vector_type(4), aligned(4)));

__device__ __forceinline__ float bcast_lane(float v, int l) {
    return __int_as_float(__builtin_amdgcn_readlane(__float_as_int(v), l));
}

// r0-proven LDS flag handshake (workgroup scope, acquire/release).
__device__ __forceinline__ void flag_set(int* f, int v) {
    if ((threadIdx.x & 63) == 0)
        __hip_atomic_store(f, v, __ATOMIC_RELEASE, __HIP_MEMORY_SCOPE_WORKGROUP);
}
__device__ __forceinline__ void flag_wait(int* f, int target) {
    while (__hip_atomic_load(f, __ATOMIC_ACQUIRE, __HIP_MEMORY_SCOPE_WORKGROUP) < target)
        __builtin_amdgcn_s_sleep(2);
}

// boustrophedon source ownership (36/35/34 pairs): bb%6 = 0..5 -> wave 0,1,2,2,1,0
__device__ __forceinline__ int bowner(int bb) {
    const int m = bb % 6;
    return (m < 3) ? m : 5 - m;
}

// ---------------- Kernel 1: memory MLP, LDS-staged weights (r6 proven) ----------------
__global__ __launch_bounds__(64) void me_mlp_kernel(
    const float* __restrict__ t,
    const float* __restrict__ w1, const float* __restrict__ b1,
    const float* __restrict__ w2, const float* __restrict__ b2,
    const float* __restrict__ w3, const float* __restrict__ b3,
    const float* __restrict__ w4, const float* __restrict__ b4,
    float* __restrict__ me)
{
    __shared__ float sw2[HID * HID], sw3[HID * HID];
    __shared__ float sw1[HID], sb1[HID], sb2[HID], sb3[HID], sw4[HID];
    __shared__ float sb4;
    const int tx = threadIdx.x;

    for (int i = tx; i < HID * HID; i += 64) { sw2[i] = w2[i]; sw3[i] = w3[i]; }
    for (int i = tx; i < HID; i += 64) {
        sw1[i] = w1[i]; sb1[i] = b1[i]; sb2[i] = b2[i];
        sb3[i] = b3[i]; sw4[i] = w4[i];
    }
    if (tx == 0) sb4 = b4[0];
    __syncthreads();

    const int r = blockIdx.x * 64 + tx;
    if (r >= MEPAD) return;
    if (r >= T_N) { me[r] = 0.0f; return; }

    const float x = t[r];
    float h1[HID], h2[HID], h3[HID];
    #pragma unroll
    for (int k = 0; k < HID; ++k) h1[k] = tanhf(fmaf(x, sw1[k], sb1[k]));
    for (int j = 0; j < HID; ++j) {
        float s = sb2[j];
        #pragma unroll
        for (int k = 0; k < HID; ++k) s = fmaf(h1[k], sw2[k * HID + j], s);
        h2[j] = tanhf(s);
    }
    for (int j = 0; j < HID; ++j) {
        float s = sb3[j];
        #pragma unroll
        for (int k = 0; k < HID; ++k) s = fmaf(h2[k], sw3[k * HID + j], s);
        h3[j] = tanhf(s);
    }
    float o = sb4;
    #pragma unroll
    for (int k = 0; k < HID; ++k) o = fmaf(h3[k], sw4[k], o);
    me[r] = 1.0f / (1.0f + expf(-o));
}

// Combined 2-system conv bb-iteration: L loaded ONCE, accumulated into
// x0..x3 (system 0) and z0..z3 (system 1). Per-system op order identical
// to the r0/r6 inner loop.
#define CONV_BB2(i0v, JTv)                                                  \
    {                                                                       \
        const int i0_ = (i0v);                                              \
        const float iv0 = Ih0[i0_ + lane];                                  \
        const float iv1 = Ih1[i0_ + lane];                                  \
        const float* gk = me + (T_N - ((JTv) - i0_) - lane);                \
        f4v L[16];                                                          \
        _Pragma("unroll")                                                   \
        for (int u = 0; u < 16; ++u) L[u] = *(const f4v*)(gk + 4 * u);      \
        _Pragma("unroll")                                                   \
        for (int g = 0; g < 8; ++g) {                                       \
            const f4v La = L[2 * g], Lb = L[2 * g + 1];                     \
            const float a0 = bcast_lane(iv0, 8 * g + 0);                    \
            const float a1 = bcast_lane(iv0, 8 * g + 1);                    \
            const float a2 = bcast_lane(iv0, 8 * g + 2);                    \
            const float a3 = bcast_lane(iv0, 8 * g + 3);                    \
            const float a4 = bcast_lane(iv0, 8 * g + 4);                    \
            const float a5 = bcast_lane(iv0, 8 * g + 5);                    \
            const float a6 = bcast_lane(iv0, 8 * g + 6);                    \
            const float a7 = bcast_lane(iv0, 8 * g + 7);                    \
            const float c0 = bcast_lane(iv1, 8 * g + 0);                    \
            const float c1 = bcast_lane(iv1, 8 * g + 1);                    \
            const float c2 = bcast_lane(iv1, 8 * g + 2);                    \
            const float c3 = bcast_lane(iv1, 8 * g + 3);                    \
            const float c4 = bcast_lane(iv1, 8 * g + 4);                    \
            const float c5 = bcast_lane(iv1, 8 * g + 5);                    \
            const float c6 = bcast_lane(iv1, 8 * g + 6);                    \
            const float c7 = bcast_lane(iv1, 8 * g + 7);                    \
            x0 = fmaf(a0, La.x, x0);  z0 = fmaf(c0, La.x, z0);              \
            x1 = fmaf(a1, La.y, x1);  z1 = fmaf(c1, La.y, z1);              \
            x2 = fmaf(a2, La.z, x2);  z2 = fmaf(c2, La.z, z2);              \
            x3 = fmaf(a3, La.w, x3);  z3 = fmaf(c3, La.w, z3);              \
            x0 = fmaf(a4, Lb.x, x0);  z0 = fmaf(c4, Lb.x, z0);              \
            x1 = fmaf(a5, Lb.y, x1);  z1 = fmaf(c5, Lb.y, z1);              \
            x2 = fmaf(a6, Lb.z, x2);  z2 = fmaf(c6, Lb.z, z2);              \
            x3 = fmaf(a7, Lb.w, x3);  z3 = fmaf(c7, Lb.w, z3);              \
        }                                                                   \
    }

// ---------------- Kernel 2: barrier-free producer/consumer pipeline ----------------
// Round-13: TWO SYSTEMS PER BLOCK, serial-wave ILP, one block per CU.
//   Evidence (r10 arithmetic): r6 is SERIAL-CHUNK-bound (~8000cy/chunk) --
//   helper New overlaps serial fully; removing it (r10) was purely additive.
//   The 8000cy >> issue(~1500) + chain(~600) gap is per-wave exposed latency
//   (readlane->SGPR hazards, W chain, L-load exposure). Fix via ILP: one
//   serial wave interleaves TWO independent systems (grid 256 = #CUs -> 1
//   block/CU, 4 waves -> exclusive SIMDs). L/L2 coefficient registers (128
//   VGPR, the dominant cost) are SHARED between systems; per-system op order
//   is bit-identical to r6. Helpers: r6 carry/burst structure, combined
//   2-system conv (shared L), boustrophedon ownership, same handshake count.
//   launch_bounds(256,1) lifts the VGPR cap (r1's spill lesson).
__global__ __launch_bounds__(256, 1) void ode_kernel(
    const float* __restrict__ t,
    const float* __restrict__ y,
    const float* __restrict__ me,
    const float* __restrict__ betap,
    const float* __restrict__ gammap,
    float* __restrict__ out)
{
    const int b0   = blockIdx.x;          // system 0
    const int b1   = blockIdx.x + NBLK;   // system 1
    const int tx   = threadIdx.x;
    const int lane = tx & 63;
    const int wv   = tx >> 6;

    __shared__ float Ih0[T_N], Sh0[T_N];     // system-0 trajectories
    __shared__ float Ih1[T_N], Sh1[T_N];     // system-1 trajectories
    __shared__ float Hs0[2][3][64];          // sys-0 helper slices, parity dbuf
    __shared__ float Hs1[2][3][64];          // sys-1 helper slices
    __shared__ int   flagI;                  // serial -> helpers (both systems)
    __shared__ int   flagH[4];               // helpers -> serial (both systems)

    const float dt  = t[0] - t[1];   // 1/1024, exact
    const float rdt = 1.0f / dt;
    const float bet = betap[0];
    const float gam = gammap[0];
    const float Af  = dt * bet;
    const float Bf  = 1.0f - dt * gam;
    const float D2  = dt * dt;
    const float kl1 = me[T_N - 1];   // kl[1]

    float S0 = y[3 * b0 + 0], I0 = y[3 * b0 + 1];
    float S1 = y[3 * b1 + 0], I1 = y[3 * b1 + 1];
    const float Rc0 = S0 + I0 + y[3 * b0 + 2];
    const float Rc1 = S1 + I1 + y[3 * b1 + 2];

    if (wv == 0) {
        #pragma unroll
        for (int m = 0; m < 3; ++m) { Hs0[0][m][lane] = 0.f; Hs1[0][m][lane] = 0.f; }
    }
    if (tx == 0) {
        Ih0[0] = I0; Sh0[0] = S0; Ih1[0] = I1; Sh1[0] = S1;
        flagI = 0; flagH[1] = flagH[2] = flagH[3] = 0;
    }
    if (tx < 3) {
        out[3 * b0 + tx] = y[3 * b0 + tx];                        // solution row 0
        out[3 * b1 + tx] = y[3 * b1 + tx];
        out[TB3 + (size_t)1023 * B_N * 3 + 3 * b0 + tx] = 0.0f;   // diff row 1023
        out[TB3 + (size_t)1023 * B_N * 3 + 3 * b1 + tx] = 0.0f;
    }
    __syncthreads();   // one-time init barrier (nothing in flight)

    if (wv == 0) {
        // ================= SERIAL WAVE: both systems, interleaved =================
        float W20 = 0.0f, W21 = 0.0f;
        for (int p = 0; p < 16; ++p) {
            const int Js = p * 64;
            if (p) {
                flag_wait(&flagH[1], p);
                flag_wait(&flagH[2], p);
                flag_wait(&flagH[3], p);
            }
            const int pb = p & 1;
            float W0 = W20 + (Hs0[pb][0][lane] + Hs0[pb][1][lane] + Hs0[pb][2][lane]);
            float W1 = W21 + (Hs1[pb][0][lane] + Hs1[pb][1][lane] + Hs1[pb][2][lane]);
            W20 = 0.0f; W21 = 0.0f;

            const float* gk  = me + (T_N - lane);        // kl[lane-q]
            const float* gk2 = me + (T_N - 64 - lane);   // kl[64+lane-q]
            f4v L[16], L2[16];
            #pragma unroll
            for (int u = 0; u < 16; ++u) {
                L[u]  = *(const f4v*)(gk  + 4 * u);
                L2[u] = *(const f4v*)(gk2 + 4 * u);
            }

            float mS0 = S0, mI0 = I0, mS1 = S1, mI1 = I1;
            float pre0 = bcast_lane(W0, 0);
            float pre1 = bcast_lane(W1, 0);

            {   // step 0 (chunk 0: initial condition), both systems
                const float A0 = p ? Af : 0.0f;
                const float B0 = p ? Bf : 1.0f;
                const float D0 = p ? D2 : 0.0f;
                const float tot0 = pre0;
                const float tot1 = pre1;
                pre0 = bcast_lane(W0, 1);
                pre1 = bcast_lane(W1, 1);
                const float SI0 = S0 * I0,        SI1 = S1 * I1;
                const float tI0 = B0 * I0,        tI1 = B0 * I1;
                const float u10 = fmaf(-A0, SI0, S0);
                const float u11 = fmaf(-A0, SI1, S1);
                I0 = fmaf(A0, SI0, tI0);          I1 = fmaf(A0, SI1, tI1);
                S0 = fmaf(D0, tot0, u10);         S1 = fmaf(D0, tot1, u11);
                if (lane == 0) { mS0 = S0; mI0 = I0; mS1 = S1; mI1 = I1; }
                W0  = fmaf(L[0].x,  I0, W0);      W1  = fmaf(L[0].x,  I1, W1);
                W20 = fmaf(L2[0].x, I0, W20);     W21 = fmaf(L2[0].x, I1, W21);
            }

#define BSTEP2(c, KV, KV2)                                                \
            {                                                             \
                const float tot0 = fmaf(kl1, I0, pre0);                   \
                const float tot1 = fmaf(kl1, I1, pre1);                   \
                pre0 = bcast_lane(W0, ((c) + 1) & 63);                    \
                pre1 = bcast_lane(W1, ((c) + 1) & 63);                    \
                const float SI0 = S0 * I0,        SI1 = S1 * I1;          \
                const float tI0 = Bf * I0,        tI1 = Bf * I1;          \
                const float u10 = fmaf(-Af, SI0, S0);                     \
                const float u11 = fmaf(-Af, SI1, S1);                     \
                I0 = fmaf(Af, SI0, tI0);          I1 = fmaf(Af, SI1, tI1);\
                S0 = fmaf(D2, tot0, u10);         S1 = fmaf(D2, tot1, u11);\
                if (lane == (c)) { mS0 = S0; mI0 = I0; mS1 = S1; mI1 = I1; }\
                W0  = fmaf((KV),  I0, W0);        W1  = fmaf((KV),  I1, W1);\
                W20 = fmaf((KV2), I0, W20);       W21 = fmaf((KV2), I1, W21);\
            }
#define BGRP2(U)                                                          \
            BSTEP2(4*(U)+0, L[U].x, L2[U].x)                              \
            BSTEP2(4*(U)+1, L[U].y, L2[U].y)                              \
            BSTEP2(4*(U)+2, L[U].z, L2[U].z)                              \
            BSTEP2(4*(U)+3, L[U].w, L2[U].w)

            BSTEP2(1, L[0].y, L2[0].y)
            BSTEP2(2, L[0].z, L2[0].z)
            BSTEP2(3, L[0].w, L2[0].w)
            BGRP2(1)  BGRP2(2)  BGRP2(3)  BGRP2(4)  BGRP2(5)
            BGRP2(6)  BGRP2(7)  BGRP2(8)  BGRP2(9)  BGRP2(10)
            BGRP2(11) BGRP2(12) BGRP2(13) BGRP2(14) BGRP2(15)
#undef BGRP2
#undef BSTEP2

            Ih0[Js + lane] = mI0;  Sh0[Js + lane] = mS0;
            Ih1[Js + lane] = mI1;  Sh1[Js + lane] = mS1;
            flag_set(&flagI, p + 1);   // release: both systems' chunk p published
        }
    } else {
        // ====== HELPER WAVES (w = wv-1): r6 carry/burst, 2 systems combined ======
        const int w = wv - 1;
        float x0 = 0.f, x1 = 0.f, x2 = 0.f, x3 = 0.f;   // sys0 carried slice
        float z0 = 0.f, z1 = 0.f, z2 = 0.f, z3 = 0.f;   // sys1 carried slice
        for (int p = 0; p < 16; ++p) {
            if (p >= 1) {
                flag_wait(&flagI, p);   // chunks 0..p-1 published (both systems)
                // ---- CRITICAL: New(p+1) = conv(bb=p-1), owner only ----
                if (p < 15 && bowner(p - 1) == w) {
                    CONV_BB2((p - 1) * 64, (p + 1) * 64)
                }
            }
            if (p < 15) {
                Hs0[(p + 1) & 1][w][lane] = (x0 + x1) + (x2 + x3);
                Hs1[(p + 1) & 1][w][lane] = (z0 + z1) + (z2 + z3);
                flag_set(&flagH[wv], p + 1);   // both systems' slice(p+1) ready
            }
            // ---- off-path: stores of chunk p-1, both systems ----
            if (p >= 1) {
                const int j = (p - 1) * 64 + lane;
                if (wv == 1) {
                    const float sa = Sh0[j], ia = Ih0[j];
                    const float sb = Sh1[j], ib = Ih1[j];
                    float* soa = out + (size_t)j * (B_N * 3) + 3 * b0;
                    float* sob = out + (size_t)j * (B_N * 3) + 3 * b1;
                    soa[0] = sa; soa[1] = ia; soa[2] = Rc0 - sa - ia;
                    sob[0] = sb; sob[1] = ib; sob[2] = Rc1 - sb - ib;
                } else if (wv == 2 && j >= 1) {
                    const float sa1 = Sh0[j], ia1 = Ih0[j];
                    const float sa0 = Sh0[j - 1], ia0 = Ih0[j - 1];
                    const float sb1 = Sh1[j], ib1 = Ih1[j];
                    const float sb0 = Sh1[j - 1], ib0 = Ih1[j - 1];
                    const float dSa = (sa1 - sa0) * rdt, dIa = (ia1 - ia0) * rdt;
                    const float dSb = (sb1 - sb0) * rdt, dIb = (ib1 - ib0) * rdt;
                    float* dfa = out + TB3 + (size_t)(j - 1) * (B_N * 3) + 3 * b0;
                    float* dfb = out + TB3 + (size_t)(j - 1) * (B_N * 3) + 3 * b1;
                    dfa[0] = dSa; dfa[1] = dIa; dfa[2] = -(dSa + dIa);
                    dfb[0] = dSb; dfb[1] = dIb; dfb[2] = -(dSb + dIb);
                }
            }
            // ---- off-path: Old(p+2) = owned bb <= p-1 ascending, register burst ----
            x0 = 0.f; x1 = 0.f; x2 = 0.f; x3 = 0.f;
            z0 = 0.f; z1 = 0.f; z2 = 0.f; z3 = 0.f;
            if (p < 14) {
                const int Jt2 = (p + 2) * 64;
                for (int bb = 0; bb <= p - 1; ++bb) {
                    if (bowner(bb) == w) { CONV_BB2(bb * 64, Jt2) }
                }
            }
        }
        // ---- epilogue: chunk 15 rows, both systems ----
        if (wv == 1 || wv == 2) {
            flag_wait(&flagI, 16);
            const int j = 960 + lane;
            if (wv == 1) {
                const float sa = Sh0[j], ia = Ih0[j];
                const float sb = Sh1[j], ib = Ih1[j];
                float* soa = out + (size_t)j * (B_N * 3) + 3 * b0;
                float* sob = out + (size_t)j * (B_N * 3) + 3 * b1;
                soa[0] = sa; soa[1] = ia; soa[2] = Rc0 - sa - ia;
                sob[0] = sb; sob[1] = ib; sob[2] = Rc1 - sb - ib;
            } else {
                const float sa1 = Sh0[j], ia1 = Ih0[j];
                const float sa0 = Sh0[j - 1], ia0 = Ih0[j - 1];
                const float sb1 = Sh1[j], ib1 = Ih1[j];
                const float sb0 = Sh1[j - 1], ib0 = Ih1[j - 1];
                const float dSa = (sa1 - sa0) * rdt, dIa = (ia1 - ia0) * rdt;
                const float dSb = (sb1 - sb0) * rdt, dIb = (ib1 - ib0) * rdt;
                float* dfa = out + TB3 + (size_t)(j - 1) * (B_N * 3) + 3 * b0;
                float* dfb = out + TB3 + (size_t)(j - 1) * (B_N * 3) + 3 * b1;
                dfa[0] = dSa; dfa[1] = dIa; dfa[2] = -(dSa + dIa);
                dfb[0] = dSb; dfb[1] = dIb; dfb[2] = -(dSb + dIb);
            }
        }
    }
}

// ---------------- launcher ----------------
extern "C" void kernel_launch(void* const* d_in, const int* in_sizes, int n_in,
                              void* d_out, int out_size, void* d_ws, size_t ws_size,
                              hipStream_t stream)
{
    const float* t   = (const float*)d_in[0];
    const float* y   = (const float*)d_in[1];
    const float* w1  = (const float*)d_in[2];
    const float* b1  = (const float*)d_in[3];
    const float* w2  = (const float*)d_in[4];
    const float* b2  = (const float*)d_in[5];
    const float* w3  = (const float*)d_in[6];
    const float* b3  = (const float*)d_in[7];
    const float* w4  = (const float*)d_in[8];
    const float* b4  = (const float*)d_in[9];
    const float* bet = (const float*)d_in[10];
    const float* gam = (const float*)d_in[11];
    float* out = (float*)d_out;
    float* me  = (float*)d_ws;   // 1152 floats of scratch (me + zero pad)

    me_mlp_kernel<<<dim3(MEPAD / 64), dim3(64), 0, stream>>>(
        t, w1, b1, w2, b2, w3, b3, w4, b4, me);
    ode_kernel<<<dim3(NBLK), dim3(256), 0, stream>>>(t, y, me, bet, gam, out);
}

// Round 14
// 139.424 us; speedup vs baseline: 1.0589x; 1.0589x over previous
//
#include <hip/hip_runtime.h>

#define T_N 1024
#define B_N 512
#define HID 20
#define TB3 (T_N * B_N * 3)   // 1572864
#define MEPAD 1152            // me + 128 zero-pad (kl[d<=0] = 0)

typedef float f4v __attribute__((ext_vector_type(4), aligned(4)));

__device__ __forceinline__ float bcast_lane(float v, int l) {
    return __int_as_float(__builtin_amdgcn_readlane(__float_as_int(v), l));
}

// r0-proven LDS flag handshake (workgroup scope, acquire/release).
__device__ __forceinline__ void flag_set(int* f, int v) {
    if ((threadIdx.x & 63) == 0)
        __hip_atomic_store(f, v, __ATOMIC_RELEASE, __HIP_MEMORY_SCOPE_WORKGROUP);
}
__device__ __forceinline__ void flag_wait(int* f, int target) {
    while (__hip_atomic_load(f, __ATOMIC_ACQUIRE, __HIP_MEMORY_SCOPE_WORKGROUP) < target)
        __builtin_amdgcn_s_sleep(2);
}

// ---------------- Kernel 1: memory MLP, LDS-staged weights (r6 proven) ----------------
__global__ __launch_bounds__(64) void me_mlp_kernel(
    const float* __restrict__ t,
    const float* __restrict__ w1, const float* __restrict__ b1,
    const float* __restrict__ w2, const float* __restrict__ b2,
    const float* __restrict__ w3, const float* __restrict__ b3,
    const float* __restrict__ w4, const float* __restrict__ b4,
    float* __restrict__ me)
{
    __shared__ float sw2[HID * HID], sw3[HID * HID];
    __shared__ float sw1[HID], sb1[HID], sb2[HID], sb3[HID], sw4[HID];
    __shared__ float sb4;
    const int tx = threadIdx.x;

    for (int i = tx; i < HID * HID; i += 64) { sw2[i] = w2[i]; sw3[i] = w3[i]; }
    for (int i = tx; i < HID; i += 64) {
        sw1[i] = w1[i]; sb1[i] = b1[i]; sb2[i] = b2[i];
        sb3[i] = b3[i]; sw4[i] = w4[i];
    }
    if (tx == 0) sb4 = b4[0];
    __syncthreads();

    const int r = blockIdx.x * 64 + tx;
    if (r >= MEPAD) return;
    if (r >= T_N) { me[r] = 0.0f; return; }

    const float x = t[r];
    float h1[HID], h2[HID], h3[HID];
    #pragma unroll
    for (int k = 0; k < HID; ++k) h1[k] = tanhf(fmaf(x, sw1[k], sb1[k]));
    for (int j = 0; j < HID; ++j) {
        float s = sb2[j];
        #pragma unroll
        for (int k = 0; k < HID; ++k) s = fmaf(h1[k], sw2[k * HID + j], s);
        h2[j] = tanhf(s);
    }
    for (int j = 0; j < HID; ++j) {
        float s = sb3[j];
        #pragma unroll
        for (int k = 0; k < HID; ++k) s = fmaf(h2[k], sw3[k * HID + j], s);
        h3[j] = tanhf(s);
    }
    float o = sb4;
    #pragma unroll
    for (int k = 0; k < HID; ++k) o = fmaf(h3[k], sw4[k], o);
    me[r] = 1.0f / (1.0f + expf(-o));
}

// One conv bb-iteration (helpers; unchanged from r6/r0).
#define CONV_BB(i0v, JTv)                                                   \
    {                                                                       \
        const int i0_ = (i0v);                                              \
        const float ihv = Ih[i0_ + lane];                                   \
        const float* gk = me + (T_N - ((JTv) - i0_) - lane);                \
        f4v L[16];                                                          \
        _Pragma("unroll")                                                   \
        for (int u = 0; u < 16; ++u) L[u] = *(const f4v*)(gk + 4 * u);      \
        _Pragma("unroll")                                                   \
        for (int g = 0; g < 8; ++g) {                                       \
            const float r0 = bcast_lane(ihv, 8 * g + 0);                    \
            const float r1 = bcast_lane(ihv, 8 * g + 1);                    \
            const float r2 = bcast_lane(ihv, 8 * g + 2);                    \
            const float r3 = bcast_lane(ihv, 8 * g + 3);                    \
            const float r4 = bcast_lane(ihv, 8 * g + 4);                    \
            const float r5 = bcast_lane(ihv, 8 * g + 5);                    \
            const float r6 = bcast_lane(ihv, 8 * g + 6);                    \
            const float r7 = bcast_lane(ihv, 8 * g + 7);                    \
            const f4v La = L[2 * g], Lb = L[2 * g + 1];                     \
            hm0 = fmaf(r0, La.x, hm0);                                      \
            hm1 = fmaf(r1, La.y, hm1);                                      \
            hm2 = fmaf(r2, La.z, hm2);                                      \
            hm3 = fmaf(r3, La.w, hm3);                                      \
            hm0 = fmaf(r4, Lb.x, hm0);                                      \
            hm1 = fmaf(r5, Lb.y, hm1);                                      \
            hm2 = fmaf(r6, Lb.z, hm2);                                      \
            hm3 = fmaf(r7, Lb.w, hm3);                                      \
        }                                                                   \
    }

// ---------------- Kernel 2: barrier-free producer/consumer pipeline ----------------
// Round-14: r6 (53.2us, best) with ONE serial-wave change: 2-step-lookahead
// readlane. Evidence (r13): serial is latency-bound (~108cy/step, ~50cy/step
// fillable); the only cross-pipe op on the per-step chain is v_readlane
// (VALU->SGPR->VALU round trip), consumed 1 step after issue in r6.
// Now: read W[c+2] at step c (contents i<=c-3), consume at step c+2 with
// scalar patch tot = kl1*I_{c+1} + fmaf(kl2, I_c, pre). The patch fma has
// IDENTICAL operands to the vector fma that previously folded kl2*I into
// W[c] -> bitwise-identical results. Readlane->use distance ~52cy.
// Helpers/handshake/launch config byte-for-byte r6.
__global__ __launch_bounds__(256, 2) void ode_kernel(
    const float* __restrict__ t,
    const float* __restrict__ y,
    const float* __restrict__ me,
    const float* __restrict__ betap,
    const float* __restrict__ gammap,
    float* __restrict__ out)
{
    const int b    = blockIdx.x;
    const int tx   = threadIdx.x;
    const int lane = tx & 63;
    const int wv   = tx >> 6;

    __shared__ float Ih[T_N];        // I trajectory
    __shared__ float Sh[T_N];        // S trajectory
    __shared__ float Hs[2][3][64];   // helper Hmain slices, parity double-buffered
    __shared__ int   flagI;          // serial -> helpers: chunks published
    __shared__ int   flagH[4];       // helpers -> serial: Hmain ready through chunk

    const float dt  = t[0] - t[1];   // 1/1024, exact
    const float rdt = 1.0f / dt;
    const float bet = betap[0];
    const float gam = gammap[0];
    const float Af  = dt * bet;
    const float Bf  = 1.0f - dt * gam;
    const float D2  = dt * dt;
    const float kl1 = me[T_N - 1];   // kl[1]
    const float kl2 = me[T_N - 2];   // kl[2] (scalar patch for 2-step lookahead)

    float S = y[3 * b + 0];
    float I = y[3 * b + 1];
    const float Rc = S + I + y[3 * b + 2];

    if (wv == 0) { Hs[0][0][lane] = 0.f; Hs[0][1][lane] = 0.f; Hs[0][2][lane] = 0.f; }
    if (tx == 0) { Ih[0] = I; Sh[0] = S; flagI = 0; flagH[1] = flagH[2] = flagH[3] = 0; }
    if (tx < 3) {
        out[3 * b + tx] = y[3 * b + tx];                        // solution row 0
        out[TB3 + (size_t)1023 * B_N * 3 + 3 * b + tx] = 0.0f;  // diff row 1023
    }
    __syncthreads();   // one-time init barrier (nothing in flight)

    if (wv == 0) {
        // ================= SERIAL WAVE (2-step-lookahead readlane) ================
        float W2 = 0.0f;
        for (int p = 0; p < 16; ++p) {
            const int Js = p * 64;
            if (p) {
                flag_wait(&flagH[1], p);
                flag_wait(&flagH[2], p);
                flag_wait(&flagH[3], p);
            }
            const int pb = p & 1;
            float W = W2 + (Hs[pb][0][lane] + Hs[pb][1][lane] + Hs[pb][2][lane]);
            W2 = 0.0f;

            const float* gk  = me + (T_N - lane);        // kl[lane-q]
            const float* gk2 = me + (T_N - 64 - lane);   // kl[64+lane-q]
            f4v L[16], L2[16];
            #pragma unroll
            for (int u = 0; u < 16; ++u) {
                L[u]  = *(const f4v*)(gk  + 4 * u);
                L2[u] = *(const f4v*)(gk2 + 4 * u);
            }

            float mS = S, mI = I;
            // Prologue: W[0] (complete), W[1] (needs kl1*I0), W[2] (needs kl2*I0+kl1*I1)
            float Im1 = 0.0f;                    // I_{c-2}; 0 entering step 1 (its
                                                 // kl2 partner is already in base W)
            const float t0 = bcast_lane(W, 0);
            float pB = bcast_lane(W, 1);         // raw pre for odd steps
            float pA = bcast_lane(W, 2);         // raw pre for even steps

            {   // step 0 (chunk 0: initial condition)
                const float A0 = p ? Af : 0.0f;
                const float B0 = p ? Bf : 1.0f;
                const float D0 = p ? D2 : 0.0f;
                const float tot = t0;
                const float SI = S * I;
                const float tI = B0 * I;
                const float u1 = fmaf(-A0, SI, S);
                I = fmaf(A0, SI, tI);
                S = fmaf(D0, tot, u1);
                if (lane == 0) { mS = S; mI = I; }
                W  = fmaf(L[0].x,  I, W);
                W2 = fmaf(L2[0].x, I, W2);
            }

// Step c (c>=1): consume PRE = raw W[c] (content i<=c-3), patch with
// kl2*I_{c-2} (bitwise = the old in-W vector fold) + kl1*I_{c-1}; then
// issue the read of W[c+2] for step c+2 (2 steps of latency slack).
#define BSTEPK(c, KV, KV2, PRE)                                           \
            {                                                             \
                const float tot = fmaf(kl1, I, fmaf(kl2, Im1, PRE));      \
                PRE = bcast_lane(W, ((c) + 2) & 63);                      \
                const float SI = S * I;                                   \
                const float tI = Bf * I;                                  \
                const float u1 = fmaf(-Af, SI, S);                        \
                Im1 = I;                                                  \
                I = fmaf(Af, SI, tI);                                     \
                S = fmaf(D2, tot, u1);                                    \
                if (lane == (c)) { mS = S; mI = I; }                      \
                W  = fmaf((KV),  I, W);                                   \
                W2 = fmaf((KV2), I, W2);                                  \
            }
// even steps consume pA, odd steps consume pB
#define BGRPK(U)                                                          \
            BSTEPK(4*(U)+0, L[U].x, L2[U].x, pA)                          \
            BSTEPK(4*(U)+1, L[U].y, L2[U].y, pB)                          \
            BSTEPK(4*(U)+2, L[U].z, L2[U].z, pA)                          \
            BSTEPK(4*(U)+3, L[U].w, L2[U].w, pB)

            BSTEPK(1, L[0].y, L2[0].y, pB)
            BSTEPK(2, L[0].z, L2[0].z, pA)
            BSTEPK(3, L[0].w, L2[0].w, pB)
            BGRPK(1)  BGRPK(2)  BGRPK(3)  BGRPK(4)  BGRPK(5)
            BGRPK(6)  BGRPK(7)  BGRPK(8)  BGRPK(9)  BGRPK(10)
            BGRPK(11) BGRPK(12) BGRPK(13) BGRPK(14) BGRPK(15)
#undef BGRPK
#undef BSTEPK

            Ih[Js + lane] = mI;
            Sh[Js + lane] = mS;
            flag_set(&flagI, p + 1);   // release: publishes Ih/Sh chunk p
        }
    } else {
        // ================= HELPER WAVES (wv 1..3) -- byte-for-byte r6 =============
        float hm0 = 0.f, hm1 = 0.f, hm2 = 0.f, hm3 = 0.f;   // carries Old(p+1)
        for (int p = 0; p < 16; ++p) {
            if (p >= 1) {
                flag_wait(&flagI, p);   // chunks 0..p-1 published
                // ---- CRITICAL: New(p+1) = conv(bb = p-1), one owning wave ----
                if (p < 15 && ((p - 1) % 3 == wv - 1)) {
                    CONV_BB((p - 1) * 64, (p + 1) * 64);
                }
            }
            if (p < 15) {
                Hs[(p + 1) & 1][wv - 1][lane] = (hm0 + hm1) + (hm2 + hm3);
                flag_set(&flagH[wv], p + 1);   // release: Hs slice ready
            }
            // ---- off-path: stores of chunk p-1 (fire-and-forget) ----
            if (p >= 1) {
                const int j = p * 64 - 64 + lane;
                if (wv == 1) {
                    const float s1 = Sh[j], i1 = Ih[j];
                    float* so = out + (size_t)j * (B_N * 3) + 3 * b;
                    so[0] = s1; so[1] = i1; so[2] = Rc - s1 - i1;
                } else if (wv == 2 && j >= 1) {
                    const float s1 = Sh[j], i1 = Ih[j];
                    const float s0 = Sh[j - 1], i0 = Ih[j - 1];
                    const float dS = (s1 - s0) * rdt;
                    const float dI = (i1 - i0) * rdt;
                    float* df = out + TB3 + (size_t)(j - 1) * (B_N * 3) + 3 * b;
                    df[0] = dS; df[1] = dI; df[2] = -(dS + dI);
                }
            }
            // ---- off-path: precompute Old(p+2) = owned bb <= p-1, ascending ----
            hm0 = 0.f; hm1 = 0.f; hm2 = 0.f; hm3 = 0.f;
            if (p < 14) {
                const int Jt2 = (p + 2) * 64;
                for (int bb = wv - 1; bb <= p - 1; bb += 3) {
                    CONV_BB(bb * 64, Jt2);
                }
            }
        }
        // ---- epilogue: chunk 15 rows ----
        if (wv == 1 || wv == 2) {
            flag_wait(&flagI, 16);
            const int j = 960 + lane;
            if (wv == 1) {
                const float s1 = Sh[j], i1 = Ih[j];
                float* so = out + (size_t)j * (B_N * 3) + 3 * b;
                so[0] = s1; so[1] = i1; so[2] = Rc - s1 - i1;
            } else {
                const float s1 = Sh[j], i1 = Ih[j];
                const float s0 = Sh[j - 1], i0 = Ih[j - 1];
                const float dS = (s1 - s0) * rdt;
                const float dI = (i1 - i0) * rdt;
                float* df = out + TB3 + (size_t)(j - 1) * (B_N * 3) + 3 * b;
                df[0] = dS; df[1] = dI; df[2] = -(dS + dI);
            }
        }
    }
}

// ---------------- launcher ----------------
extern "C" void kernel_launch(void* const* d_in, const int* in_sizes, int n_in,
                              void* d_out, int out_size, void* d_ws, size_t ws_size,
                              hipStream_t stream)
{
    const float* t   = (const float*)d_in[0];
    const float* y   = (const float*)d_in[1];
    const float* w1  = (const float*)d_in[2];
    const float* b1  = (const float*)d_in[3];
    const float* w2  = (const float*)d_in[4];
    const float* b2  = (const float*)d_in[5];
    const float* w3  = (const float*)d_in[6];
    const float* b3  = (const float*)d_in[7];
    const float* w4  = (const float*)d_in[8];
    const float* b4  = (const float*)d_in[9];
    const float* bet = (const float*)d_in[10];
    const float* gam = (const float*)d_in[11];
    float* out = (float*)d_out;
    float* me  = (float*)d_ws;   // 1152 floats of scratch (me + zero pad)

    me_mlp_kernel<<<dim3(MEPAD / 64), dim3(64), 0, stream>>>(
        t, w1, b1, w2, b2, w3, b3, w4, b4, me);
    ode_kernel<<<dim3(B_N), dim3(256), 0, stream>>>(t, y, me, bet, gam, out);
}